// Round 1
// baseline (717.196 us; speedup 1.0000x reference)
//
#include <hip/hip_runtime.h>

typedef short bf16x8 __attribute__((ext_vector_type(8)));
typedef float f32x4 __attribute__((ext_vector_type(4)));
typedef unsigned short u16;

__device__ __forceinline__ u16 f2bf(float f) {
  unsigned u = __builtin_bit_cast(unsigned, f);
  u += 0x7fffu + ((u >> 16) & 1u);
  return (u16)(u >> 16);
}

__device__ __forceinline__ void async16(const void* g, void* l) {
  __builtin_amdgcn_global_load_lds(
      (const __attribute__((address_space(1))) void*)g,
      (__attribute__((address_space(3))) void*)l, 16, 0, 0);
}

// ---------------- convert x: f32 -> bf16, 4 elems/thread ----------------
__global__ __launch_bounds__(256) void k_cvt(const float* __restrict__ src,
                                             u16* __restrict__ dst, int n4) {
  int i = blockIdx.x * blockDim.x + threadIdx.x;
  int stride = gridDim.x * blockDim.x;
  for (; i < n4; i += stride) {
    float4 f = ((const float4*)src)[i];
    ushort4 o;
    o.x = f2bf(f.x); o.y = f2bf(f.y); o.z = f2bf(f.z); o.w = f2bf(f.w);
    ((ushort4*)dst)[i] = o;
  }
}

// ---------- transpose+convert: src[R][C] f32 -> dst[C][R] bf16 ----------
__global__ __launch_bounds__(256) void k_tcvt(const float* __restrict__ src,
                                              u16* __restrict__ dst,
                                              int R, int C) {
  __shared__ float tile[64][65];
  int c0 = blockIdx.x * 64, r0 = blockIdx.y * 64;
  int tx = threadIdx.x & 63, ty = threadIdx.x >> 6;
#pragma unroll
  for (int i = 0; i < 64; i += 4)
    tile[ty + i][tx] = src[(size_t)(r0 + ty + i) * C + c0 + tx];
  __syncthreads();
#pragma unroll
  for (int i = 0; i < 64; i += 4)
    dst[(size_t)(c0 + ty + i) * R + r0 + tx] = f2bf(tile[tx][ty + i]);
}

// ---------------- m97-structure GEMM: C = A @ Bt^T (+bias) --------------
// A [M][2048] bf16 row-major, Bt [N][2048] bf16 row-major.
// EPI=0: scatter into q (scaled), k, vt(=transposed V). EPI=1: f32 out.
template <int EPI>
__global__ __launch_bounds__(256) void k_gemm(
    const u16* __restrict__ A, const u16* __restrict__ Bt,
    const float* __restrict__ bias,
    u16* __restrict__ qb, u16* __restrict__ kb, u16* __restrict__ vtb,
    float* __restrict__ fout) {
  constexpr int K = 2048;
  __shared__ u16 at[128 * 32];
  __shared__ u16 bts[128 * 32];
  const int tid = threadIdx.x;
  const int lane = tid & 63, w = tid >> 6;
  const int lo = lane & 15, g = lane >> 4;
  const int wr = w >> 1, wc = w & 1;
  const int rm0 = blockIdx.y * 128, cn0 = blockIdx.x * 128;
  f32x4 acc[4][4];
#pragma unroll
  for (int m = 0; m < 4; m++)
#pragma unroll
    for (int n = 0; n < 4; n++) {
      acc[m][n][0] = 0.f; acc[m][n][1] = 0.f;
      acc[m][n][2] = 0.f; acc[m][n][3] = 0.f;
    }
  for (int kt = 0; kt < K; kt += 32) {
#pragma unroll
    for (int it = 0; it < 2; it++) {
      int cb = w * 64 + it * 256;   // wave-uniform chunk base
      int ch = cb + lane;
      int row = ch >> 2, sub = ch & 3;
      async16(A + (size_t)(rm0 + row) * K + kt + sub * 8, (char*)at + (size_t)cb * 16);
      async16(Bt + (size_t)(cn0 + row) * K + kt + sub * 8, (char*)bts + (size_t)cb * 16);
    }
    __syncthreads();
    bf16x8 af[4], bfr[4];
#pragma unroll
    for (int m = 0; m < 4; m++)
      af[m] = *(const bf16x8*)((const char*)at + (wr * 64 + m * 16 + lo) * 64 + g * 16);
#pragma unroll
    for (int n = 0; n < 4; n++)
      bfr[n] = *(const bf16x8*)((const char*)bts + (wc * 64 + n * 16 + lo) * 64 + g * 16);
#pragma unroll
    for (int m = 0; m < 4; m++)
#pragma unroll
      for (int n = 0; n < 4; n++)
        acc[m][n] = __builtin_amdgcn_mfma_f32_16x16x32_bf16(af[m], bfr[n], acc[m][n], 0, 0, 0);
    __syncthreads();
  }
  // epilogue: C/D layout col=lane&15, row=(lane>>4)*4+reg  [m89-verified]
#pragma unroll
  for (int n = 0; n < 4; n++) {
    int col = cn0 + wc * 64 + n * 16 + lo;
    float bcol = bias[col];
#pragma unroll
    for (int m = 0; m < 4; m++) {
      int rowb = rm0 + wr * 64 + m * 16 + g * 4;
#pragma unroll
      for (int r = 0; r < 4; r++) {
        int rr = rowb + r;
        float v = acc[m][n][r] + bcol;
        if constexpr (EPI == 0) {
          int which = col >> 11;
          int hc = col & 2047, d = hc & 127;
          int bh = ((rr >> 11) << 4) | (hc >> 7);
          int qp = rr & 2047;
          if (which == 0)
            qb[(size_t)bh * 262144 + (size_t)qp * 128 + d] = f2bf(v * 0.08838834764831845f);
          else if (which == 1)
            kb[(size_t)bh * 262144 + (size_t)qp * 128 + d] = f2bf(v);
          else
            vtb[(size_t)bh * 262144 + (size_t)d * 2048 + qp] = f2bf(v);
        } else {
          fout[(size_t)rr * 2048 + col] = v;
        }
      }
    }
  }
}

// ---------------- flash attention: 4 waves x 16 Q-rows, KVBLK=64 --------
// q,k: [BH][2048][128] bf16 (q pre-scaled); vt: [BH][128][2048] bf16.
// K-tile LDS swizzle: byte ^= ((kv&7)<<4)  (kills 16-way conflict, 256B rows)
// Vt-tile LDS swizzle: byte ^= ((d&3)<<4)  (8-way -> ~2-way, 128B rows)
__global__ __launch_bounds__(256) void k_attn(
    const u16* __restrict__ qg, const u16* __restrict__ kg,
    const u16* __restrict__ vtg, u16* __restrict__ og) {
  __shared__ u16 ktile[64 * 128];
  __shared__ u16 vtt[128 * 64];
  __shared__ u16 plds[4][16][72];   // +8 pad: conflict-free A-frag reads
  const int bh = blockIdx.y;
  const int b = bh >> 4, h = bh & 15;
  const u16* Q = qg + (size_t)bh * 262144;
  const u16* Kp = kg + (size_t)bh * 262144;
  const u16* VT = vtg + (size_t)bh * 262144;
  const int tid = threadIdx.x;
  const int lane = tid & 63, w = tid >> 6;
  const int lo = lane & 15, g = lane >> 4;
  const int q0 = blockIdx.x * 64 + w * 16;

  bf16x8 qf[4];
#pragma unroll
  for (int c = 0; c < 4; c++)
    qf[c] = *(const bf16x8*)(Q + (size_t)(q0 + lo) * 128 + c * 32 + g * 8);

  f32x4 o[8];
#pragma unroll
  for (int n = 0; n < 8; n++) { o[n][0] = 0.f; o[n][1] = 0.f; o[n][2] = 0.f; o[n][3] = 0.f; }
  float mrow[4] = {-1e30f, -1e30f, -1e30f, -1e30f};
  float lrow[4] = {0.f, 0.f, 0.f, 0.f};

  for (int kv0 = 0; kv0 < 2048; kv0 += 64) {
#pragma unroll
    for (int it = 0; it < 4; it++) {
      int cb = w * 64 + it * 256;
      int ch = cb + lane;
      {
        int kv = ch >> 4, s = ch & 15;  // pre-swizzled source, linear LDS dest
        async16(Kp + (size_t)(kv0 + kv) * 128 + (s ^ (kv & 7)) * 8,
                (char*)ktile + (size_t)cb * 16);
      }
      {
        int d = ch >> 3, s = ch & 7;
        async16(VT + (size_t)d * 2048 + kv0 + (s ^ (d & 3)) * 8,
                (char*)vtt + (size_t)cb * 16);
      }
    }
    __syncthreads();
    // S = Q K^T  (4 n-frags of 16 kv, 4 K-chunks of 32)
    f32x4 sa[4];
#pragma unroll
    for (int n = 0; n < 4; n++) { sa[n][0] = 0.f; sa[n][1] = 0.f; sa[n][2] = 0.f; sa[n][3] = 0.f; }
#pragma unroll
    for (int c = 0; c < 4; c++)
#pragma unroll
      for (int n = 0; n < 4; n++) {
        int kv = n * 16 + lo;
        int phys = kv * 256 + ((c * 64 + g * 16) ^ ((kv & 7) << 4));
        bf16x8 kf = *(const bf16x8*)((const char*)ktile + phys);
        sa[n] = __builtin_amdgcn_mfma_f32_16x16x32_bf16(qf[c], kf, sa[n], 0, 0, 0);
      }
    // online softmax (rows = g*4+r, cols across 16-lane group)
    float tmax[4];
#pragma unroll
    for (int r = 0; r < 4; r++)
      tmax[r] = fmaxf(fmaxf(sa[0][r], sa[1][r]), fmaxf(sa[2][r], sa[3][r]));
#pragma unroll
    for (int off = 1; off < 16; off <<= 1)
#pragma unroll
      for (int r = 0; r < 4; r++)
        tmax[r] = fmaxf(tmax[r], __shfl_xor(tmax[r], off));
    float mnew[4], corr[4], psum[4];
#pragma unroll
    for (int r = 0; r < 4; r++) {
      mnew[r] = fmaxf(mrow[r], tmax[r]);
      corr[r] = __expf(mrow[r] - mnew[r]);
      psum[r] = 0.f;
    }
#pragma unroll
    for (int n = 0; n < 4; n++)
#pragma unroll
      for (int r = 0; r < 4; r++) {
        float p = __expf(sa[n][r] - mnew[r]);
        psum[r] += p;
        plds[w][g * 4 + r][lo + 16 * n] = f2bf(p);
      }
#pragma unroll
    for (int off = 1; off < 16; off <<= 1)
#pragma unroll
      for (int r = 0; r < 4; r++)
        psum[r] += __shfl_xor(psum[r], off);
#pragma unroll
    for (int r = 0; r < 4; r++) {
      lrow[r] = lrow[r] * corr[r] + psum[r];
      mrow[r] = mnew[r];
    }
#pragma unroll
    for (int n = 0; n < 8; n++)
#pragma unroll
      for (int r = 0; r < 4; r++)
        o[n][r] *= corr[r];
    // O += P V  (P via LDS relayout to A-frags; V from swizzled Vt tile)
#pragma unroll
    for (int c2 = 0; c2 < 2; c2++) {
      bf16x8 pf = *(const bf16x8*)&plds[w][lo][c2 * 32 + g * 8];
#pragma unroll
      for (int n = 0; n < 8; n++) {
        int d = n * 16 + lo;
        int phys = d * 128 + ((c2 * 64 + g * 16) ^ ((d & 3) << 4));
        bf16x8 vf = *(const bf16x8*)((const char*)vtt + phys);
        o[n] = __builtin_amdgcn_mfma_f32_16x16x32_bf16(pf, vf, o[n], 0, 0, 0);
      }
    }
    __syncthreads();
  }
  // epilogue: att[b*2048+q][h*128+d] bf16
#pragma unroll
  for (int r = 0; r < 4; r++) {
    float inv = 1.0f / lrow[r];
    int qrow = q0 + g * 4 + r;
    size_t base = ((size_t)(b * 2048 + qrow)) * 2048 + h * 128;
#pragma unroll
    for (int n = 0; n < 8; n++)
      og[base + n * 16 + lo] = f2bf(o[n][r] * inv);
  }
}

extern "C" void kernel_launch(void* const* d_in, const int* in_sizes, int n_in,
                              void* d_out, int out_size, void* d_ws, size_t ws_size,
                              hipStream_t stream) {
  const float* x      = (const float*)d_in[0];   // [4,2048,2048]
  const float* w_qkv  = (const float*)d_in[1];   // [2048,6144]
  const float* b_qkv  = (const float*)d_in[2];   // [6144]
  const float* w_proj = (const float*)d_in[3];   // [2048,2048]
  const float* b_proj = (const float*)d_in[4];   // [2048]
  float* out = (float*)d_out;

  char* p = (char*)d_ws;
  u16* xb     = (u16*)p; p += (size_t)8192 * 2048 * 2;   // x bf16; later reused as att
  u16* wqkvT  = (u16*)p; p += (size_t)6144 * 2048 * 2;
  u16* wprojT = (u16*)p; p += (size_t)2048 * 2048 * 2;
  u16* qb     = (u16*)p; p += (size_t)64 * 2048 * 128 * 2;
  u16* kb     = (u16*)p; p += (size_t)64 * 2048 * 128 * 2;
  u16* vtb    = (u16*)p; p += (size_t)64 * 2048 * 128 * 2;  // total 160 MiB

  k_cvt<<<2048, 256, 0, stream>>>(x, xb, (8192 * 2048) / 4);
  k_tcvt<<<dim3(6144 / 64, 2048 / 64), 256, 0, stream>>>(w_qkv, wqkvT, 2048, 6144);
  k_tcvt<<<dim3(2048 / 64, 2048 / 64), 256, 0, stream>>>(w_proj, wprojT, 2048, 2048);
  k_gemm<0><<<dim3(48, 64), 256, 0, stream>>>(xb, wqkvT, b_qkv, qb, kb, vtb, nullptr);
  k_attn<<<dim3(32, 64), 256, 0, stream>>>(qb, kb, vtb, xb);
  k_gemm<1><<<dim3(16, 64), 256, 0, stream>>>(xb, wprojT, b_proj, nullptr, nullptr, nullptr, out);
}

// Round 2
// 599.391 us; speedup vs baseline: 1.1965x; 1.1965x over previous
//
#include <hip/hip_runtime.h>

typedef short bf16x8 __attribute__((ext_vector_type(8)));
typedef float f32x4 __attribute__((ext_vector_type(4)));
typedef float f32x16 __attribute__((ext_vector_type(16)));
typedef unsigned int u32x4 __attribute__((ext_vector_type(4)));
typedef unsigned short u16;
typedef unsigned int u32;

__device__ __forceinline__ u16 f2bf(float f) {
  unsigned u = __builtin_bit_cast(unsigned, f);
  u += 0x7fffu + ((u >> 16) & 1u);
  return (u16)(u >> 16);
}

__device__ __forceinline__ void async16(const void* g, void* l) {
  __builtin_amdgcn_global_load_lds(
      (const __attribute__((address_space(1))) void*)g,
      (__attribute__((address_space(3))) void*)l, 16, 0, 0);
}

// ---------------- convert x: f32 -> bf16, 4 elems/thread ----------------
__global__ __launch_bounds__(256) void k_cvt(const float* __restrict__ src,
                                             u16* __restrict__ dst, int n4) {
  int i = blockIdx.x * blockDim.x + threadIdx.x;
  int stride = gridDim.x * blockDim.x;
  for (; i < n4; i += stride) {
    float4 f = ((const float4*)src)[i];
    ushort4 o;
    o.x = f2bf(f.x); o.y = f2bf(f.y); o.z = f2bf(f.z); o.w = f2bf(f.w);
    ((ushort4*)dst)[i] = o;
  }
}

// ---------- transpose+convert: src[R][C] f32 -> dst[C][R] bf16 ----------
__global__ __launch_bounds__(256) void k_tcvt(const float* __restrict__ src,
                                              u16* __restrict__ dst,
                                              int R, int C) {
  __shared__ float tile[64][65];
  int c0 = blockIdx.x * 64, r0 = blockIdx.y * 64;
  int tx = threadIdx.x & 63, ty = threadIdx.x >> 6;
#pragma unroll
  for (int i = 0; i < 64; i += 4)
    tile[ty + i][tx] = src[(size_t)(r0 + ty + i) * C + c0 + tx];
  __syncthreads();
#pragma unroll
  for (int i = 0; i < 64; i += 4)
    dst[(size_t)(c0 + ty + i) * R + r0 + tx] = f2bf(tile[tx][ty + i]);
}

// ---------------- m97-structure GEMM: C = A @ Bt^T (+bias) --------------
// A [M][2048] bf16 row-major, Bt [N][2048] bf16 row-major.
// EPI=0: scatter into q (scaled to log2-domain), k, vt. EPI=1: f32 out.
template <int EPI>
__global__ __launch_bounds__(256) void k_gemm(
    const u16* __restrict__ A, const u16* __restrict__ Bt,
    const float* __restrict__ bias,
    u16* __restrict__ qb, u16* __restrict__ kb, u16* __restrict__ vtb,
    float* __restrict__ fout) {
  constexpr int K = 2048;
  __shared__ u16 at[128 * 32];
  __shared__ u16 bts[128 * 32];
  const int tid = threadIdx.x;
  const int lane = tid & 63, w = tid >> 6;
  const int lo = lane & 15, g = lane >> 4;
  const int wr = w >> 1, wc = w & 1;
  const int rm0 = blockIdx.y * 128, cn0 = blockIdx.x * 128;
  f32x4 acc[4][4];
#pragma unroll
  for (int m = 0; m < 4; m++)
#pragma unroll
    for (int n = 0; n < 4; n++) {
      acc[m][n][0] = 0.f; acc[m][n][1] = 0.f;
      acc[m][n][2] = 0.f; acc[m][n][3] = 0.f;
    }
  for (int kt = 0; kt < K; kt += 32) {
#pragma unroll
    for (int it = 0; it < 2; it++) {
      int cb = w * 64 + it * 256;   // wave-uniform chunk base
      int ch = cb + lane;
      int row = ch >> 2, sub = ch & 3;
      async16(A + (size_t)(rm0 + row) * K + kt + sub * 8, (char*)at + (size_t)cb * 16);
      async16(Bt + (size_t)(cn0 + row) * K + kt + sub * 8, (char*)bts + (size_t)cb * 16);
    }
    __syncthreads();
    bf16x8 af[4], bfr[4];
#pragma unroll
    for (int m = 0; m < 4; m++)
      af[m] = *(const bf16x8*)((const char*)at + (wr * 64 + m * 16 + lo) * 64 + g * 16);
#pragma unroll
    for (int n = 0; n < 4; n++)
      bfr[n] = *(const bf16x8*)((const char*)bts + (wc * 64 + n * 16 + lo) * 64 + g * 16);
#pragma unroll
    for (int m = 0; m < 4; m++)
#pragma unroll
      for (int n = 0; n < 4; n++)
        acc[m][n] = __builtin_amdgcn_mfma_f32_16x16x32_bf16(af[m], bfr[n], acc[m][n], 0, 0, 0);
    __syncthreads();
  }
  // epilogue: C/D layout col=lane&15, row=(lane>>4)*4+reg  [m89-verified]
#pragma unroll
  for (int n = 0; n < 4; n++) {
    int col = cn0 + wc * 64 + n * 16 + lo;
    float bcol = bias[col];
#pragma unroll
    for (int m = 0; m < 4; m++) {
      int rowb = rm0 + wr * 64 + m * 16 + g * 4;
#pragma unroll
      for (int r = 0; r < 4; r++) {
        int rr = rowb + r;
        float v = acc[m][n][r] + bcol;
        if constexpr (EPI == 0) {
          int which = col >> 11;
          int hc = col & 2047, d = hc & 127;
          int bh = ((rr >> 11) << 4) | (hc >> 7);
          int qp = rr & 2047;
          if (which == 0)  // scale * log2(e): softmax runs in exp2 domain
            qb[(size_t)bh * 262144 + (size_t)qp * 128 + d] = f2bf(v * 0.12751743f);
          else if (which == 1)
            kb[(size_t)bh * 262144 + (size_t)qp * 128 + d] = f2bf(v);
          else
            vtb[(size_t)bh * 262144 + (size_t)d * 2048 + qp] = f2bf(v);
        } else {
          fout[(size_t)rr * 2048 + col] = v;
        }
      }
    }
  }
}

// ------------- flash attention: 8 waves x 32 Q-rows, 32x32 MFMA ---------
// Swapped QK^T (S^T = K·Q^T) and swapped PV (O^T = V^T·P^T): softmax state
// is per-lane (q = lane&31). P relayout fully in-register via
// v_cvt_pk_bf16_f32 + v_permlane32_swap_b32 (T12).
// K tile [64][128]: 16 slots/row, swizzle slot^ (kv&7). VT tile [128][64]:
// 8 slots/row, swizzle slot ^ (d&7). Both conflict-free for b128 frag reads.
__global__ __launch_bounds__(512) void k_attn(
    const u16* __restrict__ qg, const u16* __restrict__ kg,
    const u16* __restrict__ vtg, u16* __restrict__ og) {
  __shared__ u16 kt[2][64 * 128];
  __shared__ u16 vt[2][128 * 64];
  const int bh = blockIdx.x;          // bh on x: q-blocks of one head share an XCD
  const int b = bh >> 4, h = bh & 15;
  const u16* Q = qg + (size_t)bh * 262144;
  const u16* Kp = kg + (size_t)bh * 262144;
  const u16* VT = vtg + (size_t)bh * 262144;
  const int tid = threadIdx.x;
  const int lane = tid & 63, w = tid >> 6;
  const int ql = lane & 31, hi = lane >> 5;
  const int q0 = blockIdx.y * 256 + w * 32;

  // staging: 1024 chunks of 16B per tile, 2 per thread
  const int c0 = tid, c1 = tid + 512;
  const int kva = c0 >> 4, ksa = c0 & 15, kvb = c1 >> 4, ksb = c1 & 15;
  const size_t koff_a = (size_t)kva * 128 + (size_t)((ksa ^ (kva & 7)) * 8);
  const size_t koff_b = (size_t)kvb * 128 + (size_t)((ksb ^ (kvb & 7)) * 8);
  const int da = c0 >> 3, sva = c0 & 7, db = c1 >> 3, svb = c1 & 7;
  const size_t voff_a = (size_t)da * 2048 + (size_t)((sva ^ (da & 7)) * 8);
  const size_t voff_b = (size_t)db * 2048 + (size_t)((svb ^ (db & 7)) * 8);

  bf16x8 qf[8];
#pragma unroll
  for (int c = 0; c < 8; c++)
    qf[c] = *(const bf16x8*)(Q + (size_t)(q0 + ql) * 128 + c * 16 + hi * 8);

  f32x16 o[4];
#pragma unroll
  for (int nd = 0; nd < 4; nd++)
#pragma unroll
    for (int r = 0; r < 16; r++) o[nd][r] = 0.f;
  float m = -1e30f, l = 0.f;

  // prologue stage
  {
    async16(Kp + koff_a, &kt[0][c0 * 8]);
    async16(Kp + koff_b, &kt[0][c1 * 8]);
    async16(VT + voff_a, &vt[0][c0 * 8]);
    async16(VT + voff_b, &vt[0][c1 * 8]);
  }
  int cur = 0;
  for (int kv0 = 0; kv0 < 2048; kv0 += 64) {
    __syncthreads();  // vmcnt(0)+barrier: tile[cur] ready, tile[cur^1] free
    if (kv0 + 64 < 2048) {
      const u16* kbp = Kp + (size_t)(kv0 + 64) * 128;
      const u16* vbp = VT + (kv0 + 64);
      int nx = cur ^ 1;
      async16(kbp + koff_a, &kt[nx][c0 * 8]);
      async16(kbp + koff_b, &kt[nx][c1 * 8]);
      async16(vbp + voff_a, &vt[nx][c0 * 8]);
      async16(vbp + voff_b, &vt[nx][c1 * 8]);
    }
    const char* ktb = (const char*)&kt[cur][0];
    const char* vtb = (const char*)&vt[cur][0];

    // ---- S^T = K · Q^T  (two 32-kv subtiles) ----
    f32x16 sacc[2];
#pragma unroll
    for (int s2 = 0; s2 < 2; s2++)
#pragma unroll
      for (int r = 0; r < 16; r++) sacc[s2][r] = 0.f;
    __builtin_amdgcn_s_setprio(1);
#pragma unroll
    for (int c = 0; c < 8; c++)
#pragma unroll
      for (int s2 = 0; s2 < 2; s2++) {
        int kv = s2 * 32 + ql;
        int phys = kv * 256 + ((c * 32 + hi * 16) ^ ((kv & 7) << 4));
        bf16x8 kf = *(const bf16x8*)(ktb + phys);
        sacc[s2] = __builtin_amdgcn_mfma_f32_32x32x16_bf16(kf, qf[c], sacc[s2], 0, 0, 0);
      }
    __builtin_amdgcn_s_setprio(0);

    // ---- online softmax (exp2 domain; per-lane q) ----
    float tm = sacc[0][0];
#pragma unroll
    for (int r = 1; r < 16; r++) tm = fmaxf(tm, sacc[0][r]);
#pragma unroll
    for (int r = 0; r < 16; r++) tm = fmaxf(tm, sacc[1][r]);
    tm = fmaxf(tm, __shfl_xor(tm, 32));
    float mnew = fmaxf(m, tm);
    float corr = exp2f(m - mnew);
    float ps = 0.f;
#pragma unroll
    for (int s2 = 0; s2 < 2; s2++)
#pragma unroll
      for (int r = 0; r < 16; r++) {
        float p = exp2f(sacc[s2][r] - mnew);
        sacc[s2][r] = p;
        ps += p;
      }
    ps += __shfl_xor(ps, 32);
    l = l * corr + ps;
    m = mnew;
#pragma unroll
    for (int nd = 0; nd < 4; nd++)
#pragma unroll
      for (int r = 0; r < 16; r++) o[nd][r] *= corr;

    // ---- P -> bf16 A/B-frags, in-register (cvt_pk + permlane32_swap) ----
    bf16x8 pf[4];
#pragma unroll
    for (int s2 = 0; s2 < 2; s2++) {
      u32 pk[8];
#pragma unroll
      for (int i = 0; i < 8; i++) {
        u32 t;
        asm("v_cvt_pk_bf16_f32 %0, %1, %2"
            : "=v"(t) : "v"(sacc[s2][2 * i]), "v"(sacc[s2][2 * i + 1]));
        pk[i] = t;
      }
#pragma unroll
      for (int ksl = 0; ksl < 2; ksl++) {
        u32 a0 = pk[4 * ksl + 0], b0 = pk[4 * ksl + 2];
        u32 a1 = pk[4 * ksl + 1], b1 = pk[4 * ksl + 3];
        asm("v_permlane32_swap_b32 %0, %1" : "+v"(a0), "+v"(b0));
        asm("v_permlane32_swap_b32 %0, %1" : "+v"(a1), "+v"(b1));
        u32x4 fr = {a0, a1, b0, b1};
        pf[s2 * 2 + ksl] = __builtin_bit_cast(bf16x8, fr);
      }
    }

    // ---- O^T += V^T · P^T ----
    __builtin_amdgcn_s_setprio(1);
#pragma unroll
    for (int nd = 0; nd < 4; nd++)
#pragma unroll
      for (int ks = 0; ks < 4; ks++) {
        int d = nd * 32 + ql;
        int phys = d * 128 + ((ks * 32 + hi * 16) ^ ((d & 7) << 4));
        bf16x8 vf = *(const bf16x8*)(vtb + phys);
        o[nd] = __builtin_amdgcn_mfma_f32_32x32x16_bf16(vf, pf[ks], o[nd], 0, 0, 0);
      }
    __builtin_amdgcn_s_setprio(0);
    cur ^= 1;
  }

  // ---- epilogue: lane owns q = q0+ql; d = 32nd + 8j2 + 4hi + (r&3) ----
  float inv = 1.0f / l;
  size_t rowbase = ((size_t)(b * 2048 + q0 + ql)) * 2048 + h * 128 + hi * 4;
#pragma unroll
  for (int nd = 0; nd < 4; nd++)
#pragma unroll
    for (int j2 = 0; j2 < 4; j2++) {
      ushort4 us;
      us.x = f2bf(o[nd][4 * j2 + 0] * inv);
      us.y = f2bf(o[nd][4 * j2 + 1] * inv);
      us.z = f2bf(o[nd][4 * j2 + 2] * inv);
      us.w = f2bf(o[nd][4 * j2 + 3] * inv);
      *(ushort4*)(og + rowbase + nd * 32 + j2 * 8) = us;
    }
}

extern "C" void kernel_launch(void* const* d_in, const int* in_sizes, int n_in,
                              void* d_out, int out_size, void* d_ws, size_t ws_size,
                              hipStream_t stream) {
  const float* x      = (const float*)d_in[0];   // [4,2048,2048]
  const float* w_qkv  = (const float*)d_in[1];   // [2048,6144]
  const float* b_qkv  = (const float*)d_in[2];   // [6144]
  const float* w_proj = (const float*)d_in[3];   // [2048,2048]
  const float* b_proj = (const float*)d_in[4];   // [2048]
  float* out = (float*)d_out;

  char* p = (char*)d_ws;
  u16* xb     = (u16*)p; p += (size_t)8192 * 2048 * 2;   // x bf16; later reused as att
  u16* wqkvT  = (u16*)p; p += (size_t)6144 * 2048 * 2;
  u16* wprojT = (u16*)p; p += (size_t)2048 * 2048 * 2;
  u16* qb     = (u16*)p; p += (size_t)64 * 2048 * 128 * 2;
  u16* kb     = (u16*)p; p += (size_t)64 * 2048 * 128 * 2;
  u16* vtb    = (u16*)p; p += (size_t)64 * 2048 * 128 * 2;  // total 160 MiB

  k_cvt<<<2048, 256, 0, stream>>>(x, xb, (8192 * 2048) / 4);
  k_tcvt<<<dim3(6144 / 64, 2048 / 64), 256, 0, stream>>>(w_qkv, wqkvT, 2048, 6144);
  k_tcvt<<<dim3(2048 / 64, 2048 / 64), 256, 0, stream>>>(w_proj, wprojT, 2048, 2048);
  k_gemm<0><<<dim3(48, 64), 256, 0, stream>>>(xb, wqkvT, b_qkv, qb, kb, vtb, nullptr);
  k_attn<<<dim3(64, 8), 512, 0, stream>>>(qb, kb, vtb, xb);
  k_gemm<1><<<dim3(16, 64), 256, 0, stream>>>(xb, wprojT, b_proj, nullptr, nullptr, nullptr, out);
}

// Round 4
// 515.743 us; speedup vs baseline: 1.3906x; 1.1622x over previous
//
#include <hip/hip_runtime.h>

typedef short bf16x8 __attribute__((ext_vector_type(8)));
typedef float f32x4 __attribute__((ext_vector_type(4)));
typedef float f32x16 __attribute__((ext_vector_type(16)));
typedef unsigned int u32x4 __attribute__((ext_vector_type(4)));
typedef unsigned short u16;
typedef unsigned int u32;

__device__ __forceinline__ u16 f2bf(float f) {
  unsigned u = __builtin_bit_cast(unsigned, f);
  u += 0x7fffu + ((u >> 16) & 1u);
  return (u16)(u >> 16);
}

__device__ __forceinline__ void async16(const void* g, void* l) {
  __builtin_amdgcn_global_load_lds(
      (const __attribute__((address_space(1))) void*)g,
      (__attribute__((address_space(3))) void*)l, 16, 0, 0);
}

// ---------------- convert x: f32 -> bf16, 4 elems/thread ----------------
__global__ __launch_bounds__(256) void k_cvt(const float* __restrict__ src,
                                             u16* __restrict__ dst, int n4) {
  int i = blockIdx.x * blockDim.x + threadIdx.x;
  int stride = gridDim.x * blockDim.x;
  for (; i < n4; i += stride) {
    float4 f = ((const float4*)src)[i];
    ushort4 o;
    o.x = f2bf(f.x); o.y = f2bf(f.y); o.z = f2bf(f.z); o.w = f2bf(f.w);
    ((ushort4*)dst)[i] = o;
  }
}

// ---------- transpose+convert: src[R][C] f32 -> dst[C][R] bf16 ----------
__global__ __launch_bounds__(256) void k_tcvt(const float* __restrict__ src,
                                              u16* __restrict__ dst,
                                              int R, int C) {
  __shared__ float tile[64][65];
  int c0 = blockIdx.x * 64, r0 = blockIdx.y * 64;
  int tx = threadIdx.x & 63, ty = threadIdx.x >> 6;
#pragma unroll
  for (int i = 0; i < 64; i += 4)
    tile[ty + i][tx] = src[(size_t)(r0 + ty + i) * C + c0 + tx];
  __syncthreads();
#pragma unroll
  for (int i = 0; i < 64; i += 4)
    dst[(size_t)(c0 + ty + i) * R + r0 + tx] = f2bf(tile[tx][ty + i]);
}

// ================= 256x256 8-phase GEMM (T2+T3+T4+T5) ===================
// A [M][2048] bf16 rm, Bt [N][2048] bf16 rm. 512 thr = 8 waves (2M x 4N).
// LDS: per operand 2 slots (K-tile parity) x 2 halves x [128][64],
// XOR-swizzled: 16B-slot ^= (row&7), written via pre-swizzled global src.
// Schedule/iter (2 K-tiles): per tile 4 phases, gray-code quadrants
// (0,0)(0,1)(1,1)(1,0); A-frags read at P0/P2 (8), B-frags at P0/P1 (4),
// reused across phases. Stage of tile t+1 issued at P0 (consumed at P4),
// t+2 at P4 (consumed next P0): issue always after the end-barrier
// following the target slot's last read; consume guarded by
// [vmcnt(0); s_barrier] with 4 phases of slack.
// K = 2048 = 32 K-tiles of BK=64 -> 16 outer iterations x 2 tiles.

__device__ __forceinline__ void stage_tile(u16* lds, const u16* gsrc, int tid) {
  const int r0 = tid >> 3, sl = tid & 7;
#pragma unroll
  for (int h = 0; h < 2; h++)
#pragma unroll
    for (int cc = 0; cc < 2; cc++) {
      int row = r0 + cc * 64;
      async16(gsrc + (size_t)(h * 128 + row) * 2048 + ((sl ^ (row & 7)) << 3),
              (char*)lds + ((size_t)(h * 1024 + row * 8 + sl) << 4));
    }
}

template <int QM>
__device__ __forceinline__ void rd_a(bf16x8 (&dst)[4][2], const u16* base,
                                     int lo, int g) {
#pragma unroll
  for (int m2 = 0; m2 < 4; m2++)
#pragma unroll
    for (int ks = 0; ks < 2; ks++) {
      int row = QM * 64 + m2 * 16 + lo;
      dst[m2][ks] = *(const bf16x8*)((const char*)base + row * 128 +
                                     (((ks * 4 + g) ^ (row & 7)) << 4));
    }
}

template <int QN>
__device__ __forceinline__ void rd_b(bf16x8 (&dst)[2][2], const u16* base,
                                     int brow_base, int lo, int g) {
#pragma unroll
  for (int n2 = 0; n2 < 2; n2++)
#pragma unroll
    for (int ks = 0; ks < 2; ks++) {
      int row = brow_base + QN * 32 + n2 * 16 + lo;
      dst[n2][ks] = *(const bf16x8*)((const char*)base + row * 128 +
                                     (((ks * 4 + g) ^ (row & 7)) << 4));
    }
}

template <int QM, int QN>
__device__ __forceinline__ void do_mm(f32x4 (&acc)[8][4], bf16x8 (&fa)[4][2],
                                      bf16x8 (&fb)[2][2]) {
  __builtin_amdgcn_s_setprio(1);
#pragma unroll
  for (int m2 = 0; m2 < 4; m2++)
#pragma unroll
    for (int n2 = 0; n2 < 2; n2++)
#pragma unroll
      for (int ks = 0; ks < 2; ks++)
        acc[QM * 4 + m2][QN * 2 + n2] = __builtin_amdgcn_mfma_f32_16x16x32_bf16(
            fa[m2][ks], fb[n2][ks], acc[QM * 4 + m2][QN * 2 + n2], 0, 0, 0);
  __builtin_amdgcn_s_setprio(0);
}

template <int EPI, int NT>
__global__ __launch_bounds__(512, 2) void k_gemm(
    const u16* __restrict__ A, const u16* __restrict__ Bt,
    const float* __restrict__ bias,
    u16* __restrict__ qb, u16* __restrict__ kb, u16* __restrict__ vtb,
    float* __restrict__ fout) {
  __shared__ u16 aL[2][2][128 * 64];
  __shared__ u16 bL[2][2][128 * 64];
  const int tid = threadIdx.x;
  const int lane = tid & 63, w = tid >> 6;
  const int lo = lane & 15, g = lane >> 4;
  const int wm = w >> 2, wn = w & 3;
  const int brow_base = (wn & 1) * 64;
  // bijective XCD swizzle (nwg = NT*32, multiple of 8)
  const int nwg = NT * 32;
  const int swz = (blockIdx.x & 7) * (nwg >> 3) + (blockIdx.x >> 3);
  const int by = swz / NT, bx = swz % NT;
  const int rm0 = by * 256, cn0 = bx * 256;
  const u16* Ab = A + (size_t)rm0 * 2048;
  const u16* Bb = Bt + (size_t)cn0 * 2048;

  f32x4 acc[8][4];
#pragma unroll
  for (int i = 0; i < 8; i++)
#pragma unroll
    for (int j = 0; j < 4; j++) {
      acc[i][j][0] = 0.f; acc[i][j][1] = 0.f;
      acc[i][j][2] = 0.f; acc[i][j][3] = 0.f;
    }

  // prologue: tile 0 -> slot 0
  stage_tile(&aL[0][0][0], Ab, tid);
  stage_tile(&bL[0][0][0], Bb, tid);

  for (int it = 0; it < 16; ++it) {   // 32 K-tiles of 64 = full K=2048
#pragma unroll
    for (int tt = 0; tt < 2; ++tt) {
      const int tn = 2 * it + tt + 1;
      const u16* aS = &aL[tt][wm][0];
      const u16* bS = &bL[tt][wn >> 1][0];
      bf16x8 fa[4][2], fb0[2][2], fb1[2][2];
      // ---- P0: drain+bar (slot tt ready), stage tile tn -> slot tt^1 ----
      asm volatile("s_waitcnt vmcnt(0)" ::: "memory");
      __builtin_amdgcn_s_barrier();
      if (tn < 32) {
        stage_tile(&aL[tt ^ 1][0][0], Ab + tn * 64, tid);
        stage_tile(&bL[tt ^ 1][0][0], Bb + tn * 64, tid);
      }
      rd_a<0>(fa, aS, lo, g);
      rd_b<0>(fb0, bS, brow_base, lo, g);
      __builtin_amdgcn_s_barrier();
      asm volatile("s_waitcnt lgkmcnt(0)" ::: "memory");
      do_mm<0, 0>(acc, fa, fb0);
      __builtin_amdgcn_s_barrier();
      // ---- P1 ----
      rd_b<1>(fb1, bS, brow_base, lo, g);
      __builtin_amdgcn_s_barrier();
      asm volatile("s_waitcnt lgkmcnt(0)" ::: "memory");
      do_mm<0, 1>(acc, fa, fb1);
      __builtin_amdgcn_s_barrier();
      // ---- P2 ----
      rd_a<1>(fa, aS, lo, g);
      __builtin_amdgcn_s_barrier();
      asm volatile("s_waitcnt lgkmcnt(0)" ::: "memory");
      do_mm<1, 1>(acc, fa, fb1);
      __builtin_amdgcn_s_barrier();
      // ---- P3 (no new reads; fb0 still live) ----
      __builtin_amdgcn_s_barrier();
      do_mm<1, 0>(acc, fa, fb0);
      __builtin_amdgcn_s_barrier();
    }
  }

  // epilogue: C/D layout col=lane&15, row=(lane>>4)*4+reg [m89-verified]
#pragma unroll
  for (int qi = 0; qi < 8; qi++) {
    const int rowb = rm0 + wm * 128 + (qi >> 2) * 64 + (qi & 3) * 16 + g * 4;
#pragma unroll
    for (int nj = 0; nj < 4; nj++) {
      const int col = cn0 + wn * 64 + (nj >> 1) * 32 + (nj & 1) * 16 + lo;
      const float bcol = bias[col];
      const float v0 = acc[qi][nj][0] + bcol, v1 = acc[qi][nj][1] + bcol;
      const float v2 = acc[qi][nj][2] + bcol, v3 = acc[qi][nj][3] + bcol;
      if constexpr (EPI == 0) {
        const int which = col >> 11;
        const int hc = col & 2047, d = hc & 127;
        const int bh = ((rowb >> 11) << 4) | (hc >> 7);
        if (which == 2) {
          ushort4 us;
          us.x = f2bf(v0); us.y = f2bf(v1); us.z = f2bf(v2); us.w = f2bf(v3);
          *(ushort4*)(vtb + (size_t)bh * 262144 + (size_t)d * 2048 +
                      (rowb & 2047)) = us;
        } else {
          u16* dst = (which == 0) ? qb : kb;
          // q pre-scaled by D^-0.5 * log2(e): softmax runs in exp2 domain
          const float sc = (which == 0) ? 0.12751743f : 1.0f;
          size_t base = (size_t)bh * 262144 + (size_t)(rowb & 2047) * 128 + d;
          dst[base] = f2bf(v0 * sc);
          dst[base + 128] = f2bf(v1 * sc);
          dst[base + 256] = f2bf(v2 * sc);
          dst[base + 384] = f2bf(v3 * sc);
        }
      } else {
        fout[(size_t)(rowb + 0) * 2048 + col] = v0;
        fout[(size_t)(rowb + 1) * 2048 + col] = v1;
        fout[(size_t)(rowb + 2) * 2048 + col] = v2;
        fout[(size_t)(rowb + 3) * 2048 + col] = v3;
      }
    }
  }
}

// ------------- flash attention: 8 waves x 32 Q-rows, 32x32 MFMA ---------
// Swapped QK^T (S^T = K·Q^T) and swapped PV (O^T = V^T·P^T): softmax state
// is per-lane (q = lane&31). P relayout fully in-register via
// v_cvt_pk_bf16_f32 + v_permlane32_swap_b32 (T12).
__global__ __launch_bounds__(512) void k_attn(
    const u16* __restrict__ qg, const u16* __restrict__ kg,
    const u16* __restrict__ vtg, u16* __restrict__ og) {
  __shared__ u16 kt[2][64 * 128];
  __shared__ u16 vt[2][128 * 64];
  const int bh = blockIdx.x;
  const int b = bh >> 4, h = bh & 15;
  const u16* Q = qg + (size_t)bh * 262144;
  const u16* Kp = kg + (size_t)bh * 262144;
  const u16* VT = vtg + (size_t)bh * 262144;
  const int tid = threadIdx.x;
  const int lane = tid & 63, w = tid >> 6;
  const int ql = lane & 31, hi = lane >> 5;
  const int q0 = blockIdx.y * 256 + w * 32;

  const int c0 = tid, c1 = tid + 512;
  const int kva = c0 >> 4, ksa = c0 & 15, kvb = c1 >> 4, ksb = c1 & 15;
  const size_t koff_a = (size_t)kva * 128 + (size_t)((ksa ^ (kva & 7)) * 8);
  const size_t koff_b = (size_t)kvb * 128 + (size_t)((ksb ^ (kvb & 7)) * 8);
  const int da = c0 >> 3, sva = c0 & 7, db = c1 >> 3, svb = c1 & 7;
  const size_t voff_a = (size_t)da * 2048 + (size_t)((sva ^ (da & 7)) * 8);
  const size_t voff_b = (size_t)db * 2048 + (size_t)((svb ^ (db & 7)) * 8);

  bf16x8 qf[8];
#pragma unroll
  for (int c = 0; c < 8; c++)
    qf[c] = *(const bf16x8*)(Q + (size_t)(q0 + ql) * 128 + c * 16 + hi * 8);

  f32x16 o[4];
#pragma unroll
  for (int nd = 0; nd < 4; nd++)
#pragma unroll
    for (int r = 0; r < 16; r++) o[nd][r] = 0.f;
  float m = -1e30f, l = 0.f;

  {
    async16(Kp + koff_a, &kt[0][c0 * 8]);
    async16(Kp + koff_b, &kt[0][c1 * 8]);
    async16(VT + voff_a, &vt[0][c0 * 8]);
    async16(VT + voff_b, &vt[0][c1 * 8]);
  }
  int cur = 0;
  for (int kv0 = 0; kv0 < 2048; kv0 += 64) {
    __syncthreads();
    if (kv0 + 64 < 2048) {
      const u16* kbp = Kp + (size_t)(kv0 + 64) * 128;
      const u16* vbp = VT + (kv0 + 64);
      int nx = cur ^ 1;
      async16(kbp + koff_a, &kt[nx][c0 * 8]);
      async16(kbp + koff_b, &kt[nx][c1 * 8]);
      async16(vbp + voff_a, &vt[nx][c0 * 8]);
      async16(vbp + voff_b, &vt[nx][c1 * 8]);
    }
    const char* ktb = (const char*)&kt[cur][0];
    const char* vtb = (const char*)&vt[cur][0];

    f32x16 sacc[2];
#pragma unroll
    for (int s2 = 0; s2 < 2; s2++)
#pragma unroll
      for (int r = 0; r < 16; r++) sacc[s2][r] = 0.f;
    __builtin_amdgcn_s_setprio(1);
#pragma unroll
    for (int c = 0; c < 8; c++)
#pragma unroll
      for (int s2 = 0; s2 < 2; s2++) {
        int kv = s2 * 32 + ql;
        int phys = kv * 256 + ((c * 32 + hi * 16) ^ ((kv & 7) << 4));
        bf16x8 kf = *(const bf16x8*)(ktb + phys);
        sacc[s2] = __builtin_amdgcn_mfma_f32_32x32x16_bf16(kf, qf[c], sacc[s2], 0, 0, 0);
      }
    __builtin_amdgcn_s_setprio(0);

    float tm = sacc[0][0];
#pragma unroll
    for (int r = 1; r < 16; r++) tm = fmaxf(tm, sacc[0][r]);
#pragma unroll
    for (int r = 0; r < 16; r++) tm = fmaxf(tm, sacc[1][r]);
    tm = fmaxf(tm, __shfl_xor(tm, 32));
    float mnew = fmaxf(m, tm);
    float corr = exp2f(m - mnew);
    float ps = 0.f;
#pragma unroll
    for (int s2 = 0; s2 < 2; s2++)
#pragma unroll
      for (int r = 0; r < 16; r++) {
        float p = exp2f(sacc[s2][r] - mnew);
        sacc[s2][r] = p;
        ps += p;
      }
    ps += __shfl_xor(ps, 32);
    l = l * corr + ps;
    m = mnew;
#pragma unroll
    for (int nd = 0; nd < 4; nd++)
#pragma unroll
      for (int r = 0; r < 16; r++) o[nd][r] *= corr;

    bf16x8 pf[4];
#pragma unroll
    for (int s2 = 0; s2 < 2; s2++) {
      u32 pk[8];
#pragma unroll
      for (int i = 0; i < 8; i++) {
        u32 t;
        asm("v_cvt_pk_bf16_f32 %0, %1, %2"
            : "=v"(t) : "v"(sacc[s2][2 * i]), "v"(sacc[s2][2 * i + 1]));
        pk[i] = t;
      }
#pragma unroll
      for (int ksl = 0; ksl < 2; ksl++) {
        u32 a0 = pk[4 * ksl + 0], b0 = pk[4 * ksl + 2];
        u32 a1 = pk[4 * ksl + 1], b1 = pk[4 * ksl + 3];
        asm("v_permlane32_swap_b32 %0, %1" : "+v"(a0), "+v"(b0));
        asm("v_permlane32_swap_b32 %0, %1" : "+v"(a1), "+v"(b1));
        u32x4 fr = {a0, a1, b0, b1};
        pf[s2 * 2 + ksl] = __builtin_bit_cast(bf16x8, fr);
      }
    }

    __builtin_amdgcn_s_setprio(1);
#pragma unroll
    for (int nd = 0; nd < 4; nd++)
#pragma unroll
      for (int ks = 0; ks < 4; ks++) {
        int d = nd * 32 + ql;
        int phys = d * 128 + ((ks * 32 + hi * 16) ^ ((d & 7) << 4));
        bf16x8 vf = *(const bf16x8*)(vtb + phys);
        o[nd] = __builtin_amdgcn_mfma_f32_32x32x16_bf16(vf, pf[ks], o[nd], 0, 0, 0);
      }
    __builtin_amdgcn_s_setprio(0);
    cur ^= 1;
  }

  float inv = 1.0f / l;
  size_t rowbase = ((size_t)(b * 2048 + q0 + ql)) * 2048 + h * 128 + hi * 4;
#pragma unroll
  for (int nd = 0; nd < 4; nd++)
#pragma unroll
    for (int j2 = 0; j2 < 4; j2++) {
      ushort4 us;
      us.x = f2bf(o[nd][4 * j2 + 0] * inv);
      us.y = f2bf(o[nd][4 * j2 + 1] * inv);
      us.z = f2bf(o[nd][4 * j2 + 2] * inv);
      us.w = f2bf(o[nd][4 * j2 + 3] * inv);
      *(ushort4*)(og + rowbase + nd * 32 + j2 * 8) = us;
    }
}

extern "C" void kernel_launch(void* const* d_in, const int* in_sizes, int n_in,
                              void* d_out, int out_size, void* d_ws, size_t ws_size,
                              hipStream_t stream) {
  const float* x      = (const float*)d_in[0];   // [4,2048,2048]
  const float* w_qkv  = (const float*)d_in[1];   // [2048,6144]
  const float* b_qkv  = (const float*)d_in[2];   // [6144]
  const float* w_proj = (const float*)d_in[3];   // [2048,2048]
  const float* b_proj = (const float*)d_in[4];   // [2048]
  float* out = (float*)d_out;

  char* p = (char*)d_ws;
  u16* xb     = (u16*)p; p += (size_t)8192 * 2048 * 2;   // x bf16; later reused as att
  u16* wqkvT  = (u16*)p; p += (size_t)6144 * 2048 * 2;
  u16* wprojT = (u16*)p; p += (size_t)2048 * 2048 * 2;
  u16* qb     = (u16*)p; p += (size_t)64 * 2048 * 128 * 2;
  u16* kb     = (u16*)p; p += (size_t)64 * 2048 * 128 * 2;
  u16* vtb    = (u16*)p; p += (size_t)64 * 2048 * 128 * 2;  // total 160 MiB

  k_cvt<<<2048, 256, 0, stream>>>(x, xb, (8192 * 2048) / 4);
  k_tcvt<<<dim3(6144 / 64, 2048 / 64), 256, 0, stream>>>(w_qkv, wqkvT, 2048, 6144);
  k_tcvt<<<dim3(2048 / 64, 2048 / 64), 256, 0, stream>>>(w_proj, wprojT, 2048, 2048);
  k_gemm<0, 24><<<768, 512, 0, stream>>>(xb, wqkvT, b_qkv, qb, kb, vtb, nullptr);
  k_attn<<<dim3(64, 8), 512, 0, stream>>>(qb, kb, vtb, xb);
  k_gemm<1, 8><<<256, 512, 0, stream>>>(xb, wprojT, b_proj, nullptr, nullptr, nullptr, out);
}

// Round 5
// 495.964 us; speedup vs baseline: 1.4461x; 1.0399x over previous
//
#include <hip/hip_runtime.h>

typedef short bf16x8 __attribute__((ext_vector_type(8)));
typedef float f32x4 __attribute__((ext_vector_type(4)));
typedef float f32x16 __attribute__((ext_vector_type(16)));
typedef unsigned int u32x4 __attribute__((ext_vector_type(4)));
typedef unsigned short u16;
typedef unsigned int u32;

__device__ __forceinline__ u16 f2bf(float f) {
  unsigned u = __builtin_bit_cast(unsigned, f);
  u += 0x7fffu + ((u >> 16) & 1u);
  return (u16)(u >> 16);
}

__device__ __forceinline__ void async16(const void* g, void* l) {
  __builtin_amdgcn_global_load_lds(
      (const __attribute__((address_space(1))) void*)g,
      (__attribute__((address_space(3))) void*)l, 16, 0, 0);
}

// ---------------- convert x: f32 -> bf16, 4 elems/thread ----------------
__global__ __launch_bounds__(256) void k_cvt(const float* __restrict__ src,
                                             u16* __restrict__ dst, int n4) {
  int i = blockIdx.x * blockDim.x + threadIdx.x;
  int stride = gridDim.x * blockDim.x;
  for (; i < n4; i += stride) {
    float4 f = ((const float4*)src)[i];
    ushort4 o;
    o.x = f2bf(f.x); o.y = f2bf(f.y); o.z = f2bf(f.z); o.w = f2bf(f.w);
    ((ushort4*)dst)[i] = o;
  }
}

// ---------- transpose+convert: src[R][C] f32 -> dst[C][R] bf16 ----------
__global__ __launch_bounds__(256) void k_tcvt(const float* __restrict__ src,
                                              u16* __restrict__ dst,
                                              int R, int C) {
  __shared__ float tile[64][65];
  int c0 = blockIdx.x * 64, r0 = blockIdx.y * 64;
  int tx = threadIdx.x & 63, ty = threadIdx.x >> 6;
#pragma unroll
  for (int i = 0; i < 64; i += 4)
    tile[ty + i][tx] = src[(size_t)(r0 + ty + i) * C + c0 + tx];
  __syncthreads();
#pragma unroll
  for (int i = 0; i < 64; i += 4)
    dst[(size_t)(c0 + ty + i) * R + r0 + tx] = f2bf(tile[tx][ty + i]);
}

// ========= 256x256 8-phase GEMM (T2+T3+T4 counted-vmcnt+T5) =============
// A [M][2048] bf16 rm, Bt [N][2048] bf16 rm. 512 thr = 8 waves (2M x 4N).
// LDS: per operand 2 slots (K-tile parity) x 2 halves x [128][64],
// XOR-swizzled: 16B-slot ^= (row&7), written via pre-swizzled global src.
// Counted pipeline (T4): at P0 of tile t, FIRST issue stage(t+1) (8 loads)
// into slot^1, THEN s_waitcnt vmcnt(8) -> waits only tile-t's 8 oldest
// loads; tile-(t+1)'s stay in flight across all 4 phases. Never drain to 0
// in the main loop (m218: drain0 == no pipeline). Last tile: vmcnt(0).
// Slot-overwrite safety: slot^1's last ds_read is at P2 of tile t-1
// (reader waits lgkmcnt(0) before MFMA) and two barriers separate it from
// the stage-issue at P0(t).

__device__ __forceinline__ void stage_tile(u16* lds, const u16* gsrc, int tid) {
  const int r0 = tid >> 3, sl = tid & 7;
#pragma unroll
  for (int h = 0; h < 2; h++)
#pragma unroll
    for (int cc = 0; cc < 2; cc++) {
      int row = r0 + cc * 64;
      async16(gsrc + (size_t)(h * 128 + row) * 2048 + ((sl ^ (row & 7)) << 3),
              (char*)lds + ((size_t)(h * 1024 + row * 8 + sl) << 4));
    }
}

template <int QM>
__device__ __forceinline__ void rd_a(bf16x8 (&dst)[4][2], const u16* base,
                                     int lo, int g) {
#pragma unroll
  for (int m2 = 0; m2 < 4; m2++)
#pragma unroll
    for (int ks = 0; ks < 2; ks++) {
      int row = QM * 64 + m2 * 16 + lo;
      dst[m2][ks] = *(const bf16x8*)((const char*)base + row * 128 +
                                     (((ks * 4 + g) ^ (row & 7)) << 4));
    }
}

template <int QN>
__device__ __forceinline__ void rd_b(bf16x8 (&dst)[2][2], const u16* base,
                                     int brow_base, int lo, int g) {
#pragma unroll
  for (int n2 = 0; n2 < 2; n2++)
#pragma unroll
    for (int ks = 0; ks < 2; ks++) {
      int row = brow_base + QN * 32 + n2 * 16 + lo;
      dst[n2][ks] = *(const bf16x8*)((const char*)base + row * 128 +
                                     (((ks * 4 + g) ^ (row & 7)) << 4));
    }
}

template <int QM, int QN>
__device__ __forceinline__ void do_mm(f32x4 (&acc)[8][4], bf16x8 (&fa)[4][2],
                                      bf16x8 (&fb)[2][2]) {
  __builtin_amdgcn_s_setprio(1);
#pragma unroll
  for (int m2 = 0; m2 < 4; m2++)
#pragma unroll
    for (int n2 = 0; n2 < 2; n2++)
#pragma unroll
      for (int ks = 0; ks < 2; ks++)
        acc[QM * 4 + m2][QN * 2 + n2] = __builtin_amdgcn_mfma_f32_16x16x32_bf16(
            fa[m2][ks], fb[n2][ks], acc[QM * 4 + m2][QN * 2 + n2], 0, 0, 0);
  __builtin_amdgcn_s_setprio(0);
}

template <int EPI, int NT>
__global__ __launch_bounds__(512, 2) void k_gemm(
    const u16* __restrict__ A, const u16* __restrict__ Bt,
    const float* __restrict__ bias,
    u16* __restrict__ qb, u16* __restrict__ kb, u16* __restrict__ vtb,
    float* __restrict__ fout) {
  __shared__ u16 aL[2][2][128 * 64];
  __shared__ u16 bL[2][2][128 * 64];
  const int tid = threadIdx.x;
  const int lane = tid & 63, w = tid >> 6;
  const int lo = lane & 15, g = lane >> 4;
  const int wm = w >> 2, wn = w & 3;
  const int brow_base = (wn & 1) * 64;
  // bijective XCD swizzle (nwg = NT*32, multiple of 8)
  const int nwg = NT * 32;
  const int swz = (blockIdx.x & 7) * (nwg >> 3) + (blockIdx.x >> 3);
  const int by = swz / NT, bx = swz % NT;
  const int rm0 = by * 256, cn0 = bx * 256;
  const u16* Ab = A + (size_t)rm0 * 2048;
  const u16* Bb = Bt + (size_t)cn0 * 2048;

  f32x4 acc[8][4];
#pragma unroll
  for (int i = 0; i < 8; i++)
#pragma unroll
    for (int j = 0; j < 4; j++) {
      acc[i][j][0] = 0.f; acc[i][j][1] = 0.f;
      acc[i][j][2] = 0.f; acc[i][j][3] = 0.f;
    }

  // prologue: tile 0 -> slot 0
  stage_tile(&aL[0][0][0], Ab, tid);
  stage_tile(&bL[0][0][0], Bb, tid);

  for (int it = 0; it < 16; ++it) {   // 32 K-tiles of 64 = full K=2048
#pragma unroll
    for (int tt = 0; tt < 2; ++tt) {
      const int tn = 2 * it + tt + 1;
      const u16* aS = &aL[tt][wm][0];
      const u16* bS = &bL[tt][wn >> 1][0];
      bf16x8 fa[4][2], fb0[2][2], fb1[2][2];
      // ---- P0: issue stage(t+1) FIRST, then counted wait on tile t ----
      if (tn < 32) {
        stage_tile(&aL[tt ^ 1][0][0], Ab + tn * 64, tid);
        stage_tile(&bL[tt ^ 1][0][0], Bb + tn * 64, tid);
        asm volatile("s_waitcnt vmcnt(8)" ::: "memory");  // tile t landed
      } else {
        asm volatile("s_waitcnt vmcnt(0)" ::: "memory");  // final tile
      }
      __builtin_amdgcn_s_barrier();
      rd_a<0>(fa, aS, lo, g);
      rd_b<0>(fb0, bS, brow_base, lo, g);
      asm volatile("s_waitcnt lgkmcnt(0)" ::: "memory");
      do_mm<0, 0>(acc, fa, fb0);
      // ---- P1 ----
      rd_b<1>(fb1, bS, brow_base, lo, g);
      asm volatile("s_waitcnt lgkmcnt(0)" ::: "memory");
      do_mm<0, 1>(acc, fa, fb1);
      // ---- P2 ----
      rd_a<1>(fa, aS, lo, g);
      asm volatile("s_waitcnt lgkmcnt(0)" ::: "memory");
      do_mm<1, 1>(acc, fa, fb1);
      // ---- P3 (no new reads; fb0 still live) ----
      do_mm<1, 0>(acc, fa, fb0);
      __builtin_amdgcn_s_barrier();   // all waves done reading slot tt
    }
  }

  // epilogue: C/D layout col=lane&15, row=(lane>>4)*4+reg [m89-verified]
#pragma unroll
  for (int qi = 0; qi < 8; qi++) {
    const int rowb = rm0 + wm * 128 + (qi >> 2) * 64 + (qi & 3) * 16 + g * 4;
#pragma unroll
    for (int nj = 0; nj < 4; nj++) {
      const int col = cn0 + wn * 64 + (nj >> 1) * 32 + (nj & 1) * 16 + lo;
      const float bcol = bias[col];
      const float v0 = acc[qi][nj][0] + bcol, v1 = acc[qi][nj][1] + bcol;
      const float v2 = acc[qi][nj][2] + bcol, v3 = acc[qi][nj][3] + bcol;
      if constexpr (EPI == 0) {
        const int which = col >> 11;
        const int hc = col & 2047, d = hc & 127;
        const int bh = ((rowb >> 11) << 4) | (hc >> 7);
        if (which == 2) {
          ushort4 us;
          us.x = f2bf(v0); us.y = f2bf(v1); us.z = f2bf(v2); us.w = f2bf(v3);
          *(ushort4*)(vtb + (size_t)bh * 262144 + (size_t)d * 2048 +
                      (rowb & 2047)) = us;
        } else {
          u16* dst = (which == 0) ? qb : kb;
          // q pre-scaled by D^-0.5 * log2(e): softmax runs in exp2 domain
          const float sc = (which == 0) ? 0.12751743f : 1.0f;
          size_t base = (size_t)bh * 262144 + (size_t)(rowb & 2047) * 128 + d;
          dst[base] = f2bf(v0 * sc);
          dst[base + 128] = f2bf(v1 * sc);
          dst[base + 256] = f2bf(v2 * sc);
          dst[base + 384] = f2bf(v3 * sc);
        }
      } else {
        fout[(size_t)(rowb + 0) * 2048 + col] = v0;
        fout[(size_t)(rowb + 1) * 2048 + col] = v1;
        fout[(size_t)(rowb + 2) * 2048 + col] = v2;
        fout[(size_t)(rowb + 3) * 2048 + col] = v3;
      }
    }
  }
}

// ------------- flash attention: 8 waves x 32 Q-rows, 32x32 MFMA ---------
// Swapped QK^T (S^T = K·Q^T) and swapped PV (O^T = V^T·P^T): softmax state
// is per-lane (q = lane&31). P relayout fully in-register via
// v_cvt_pk_bf16_f32 + v_permlane32_swap_b32 (T12).
__global__ __launch_bounds__(512) void k_attn(
    const u16* __restrict__ qg, const u16* __restrict__ kg,
    const u16* __restrict__ vtg, u16* __restrict__ og) {
  __shared__ u16 kt[2][64 * 128];
  __shared__ u16 vt[2][128 * 64];
  const int bh = blockIdx.x;
  const int b = bh >> 4, h = bh & 15;
  const u16* Q = qg + (size_t)bh * 262144;
  const u16* Kp = kg + (size_t)bh * 262144;
  const u16* VT = vtg + (size_t)bh * 262144;
  const int tid = threadIdx.x;
  const int lane = tid & 63, w = tid >> 6;
  const int ql = lane & 31, hi = lane >> 5;
  const int q0 = blockIdx.y * 256 + w * 32;

  const int c0 = tid, c1 = tid + 512;
  const int kva = c0 >> 4, ksa = c0 & 15, kvb = c1 >> 4, ksb = c1 & 15;
  const size_t koff_a = (size_t)kva * 128 + (size_t)((ksa ^ (kva & 7)) * 8);
  const size_t koff_b = (size_t)kvb * 128 + (size_t)((ksb ^ (kvb & 7)) * 8);
  const int da = c0 >> 3, sva = c0 & 7, db = c1 >> 3, svb = c1 & 7;
  const size_t voff_a = (size_t)da * 2048 + (size_t)((sva ^ (da & 7)) * 8);
  const size_t voff_b = (size_t)db * 2048 + (size_t)((svb ^ (db & 7)) * 8);

  bf16x8 qf[8];
#pragma unroll
  for (int c = 0; c < 8; c++)
    qf[c] = *(const bf16x8*)(Q + (size_t)(q0 + ql) * 128 + c * 16 + hi * 8);

  f32x16 o[4];
#pragma unroll
  for (int nd = 0; nd < 4; nd++)
#pragma unroll
    for (int r = 0; r < 16; r++) o[nd][r] = 0.f;
  float m = -1e30f, l = 0.f;

  {
    async16(Kp + koff_a, &kt[0][c0 * 8]);
    async16(Kp + koff_b, &kt[0][c1 * 8]);
    async16(VT + voff_a, &vt[0][c0 * 8]);
    async16(VT + voff_b, &vt[0][c1 * 8]);
  }
  int cur = 0;
  for (int kv0 = 0; kv0 < 2048; kv0 += 64) {
    __syncthreads();
    if (kv0 + 64 < 2048) {
      const u16* kbp = Kp + (size_t)(kv0 + 64) * 128;
      const u16* vbp = VT + (kv0 + 64);
      int nx = cur ^ 1;
      async16(kbp + koff_a, &kt[nx][c0 * 8]);
      async16(kbp + koff_b, &kt[nx][c1 * 8]);
      async16(vbp + voff_a, &vt[nx][c0 * 8]);
      async16(vbp + voff_b, &vt[nx][c1 * 8]);
    }
    const char* ktb = (const char*)&kt[cur][0];
    const char* vtb = (const char*)&vt[cur][0];

    f32x16 sacc[2];
#pragma unroll
    for (int s2 = 0; s2 < 2; s2++)
#pragma unroll
      for (int r = 0; r < 16; r++) sacc[s2][r] = 0.f;
    __builtin_amdgcn_s_setprio(1);
#pragma unroll
    for (int c = 0; c < 8; c++)
#pragma unroll
      for (int s2 = 0; s2 < 2; s2++) {
        int kv = s2 * 32 + ql;
        int phys = kv * 256 + ((c * 32 + hi * 16) ^ ((kv & 7) << 4));
        bf16x8 kf = *(const bf16x8*)(ktb + phys);
        sacc[s2] = __builtin_amdgcn_mfma_f32_32x32x16_bf16(kf, qf[c], sacc[s2], 0, 0, 0);
      }
    __builtin_amdgcn_s_setprio(0);

    float tm = sacc[0][0];
#pragma unroll
    for (int r = 1; r < 16; r++) tm = fmaxf(tm, sacc[0][r]);
#pragma unroll
    for (int r = 0; r < 16; r++) tm = fmaxf(tm, sacc[1][r]);
    tm = fmaxf(tm, __shfl_xor(tm, 32));
    float mnew = fmaxf(m, tm);
    float corr = exp2f(m - mnew);
    float ps = 0.f;
#pragma unroll
    for (int s2 = 0; s2 < 2; s2++)
#pragma unroll
      for (int r = 0; r < 16; r++) {
        float p = exp2f(sacc[s2][r] - mnew);
        sacc[s2][r] = p;
        ps += p;
      }
    ps += __shfl_xor(ps, 32);
    l = l * corr + ps;
    m = mnew;
#pragma unroll
    for (int nd = 0; nd < 4; nd++)
#pragma unroll
      for (int r = 0; r < 16; r++) o[nd][r] *= corr;

    bf16x8 pf[4];
#pragma unroll
    for (int s2 = 0; s2 < 2; s2++) {
      u32 pk[8];
#pragma unroll
      for (int i = 0; i < 8; i++) {
        u32 t;
        asm("v_cvt_pk_bf16_f32 %0, %1, %2"
            : "=v"(t) : "v"(sacc[s2][2 * i]), "v"(sacc[s2][2 * i + 1]));
        pk[i] = t;
      }
#pragma unroll
      for (int ksl = 0; ksl < 2; ksl++) {
        u32 a0 = pk[4 * ksl + 0], b0 = pk[4 * ksl + 2];
        u32 a1 = pk[4 * ksl + 1], b1 = pk[4 * ksl + 3];
        asm("v_permlane32_swap_b32 %0, %1" : "+v"(a0), "+v"(b0));
        asm("v_permlane32_swap_b32 %0, %1" : "+v"(a1), "+v"(b1));
        u32x4 fr = {a0, a1, b0, b1};
        pf[s2 * 2 + ksl] = __builtin_bit_cast(bf16x8, fr);
      }
    }

    __builtin_amdgcn_s_setprio(1);
#pragma unroll
    for (int nd = 0; nd < 4; nd++)
#pragma unroll
      for (int ks = 0; ks < 4; ks++) {
        int d = nd * 32 + ql;
        int phys = d * 128 + ((ks * 32 + hi * 16) ^ ((d & 7) << 4));
        bf16x8 vf = *(const bf16x8*)(vtb + phys);
        o[nd] = __builtin_amdgcn_mfma_f32_32x32x16_bf16(vf, pf[ks], o[nd], 0, 0, 0);
      }
    __builtin_amdgcn_s_setprio(0);
    cur ^= 1;
  }

  float inv = 1.0f / l;
  size_t rowbase = ((size_t)(b * 2048 + q0 + ql)) * 2048 + h * 128 + hi * 4;
#pragma unroll
  for (int nd = 0; nd < 4; nd++)
#pragma unroll
    for (int j2 = 0; j2 < 4; j2++) {
      ushort4 us;
      us.x = f2bf(o[nd][4 * j2 + 0] * inv);
      us.y = f2bf(o[nd][4 * j2 + 1] * inv);
      us.z = f2bf(o[nd][4 * j2 + 2] * inv);
      us.w = f2bf(o[nd][4 * j2 + 3] * inv);
      *(ushort4*)(og + rowbase + nd * 32 + j2 * 8) = us;
    }
}

extern "C" void kernel_launch(void* const* d_in, const int* in_sizes, int n_in,
                              void* d_out, int out_size, void* d_ws, size_t ws_size,
                              hipStream_t stream) {
  const float* x      = (const float*)d_in[0];   // [4,2048,2048]
  const float* w_qkv  = (const float*)d_in[1];   // [2048,6144]
  const float* b_qkv  = (const float*)d_in[2];   // [6144]
  const float* w_proj = (const float*)d_in[3];   // [2048,2048]
  const float* b_proj = (const float*)d_in[4];   // [2048]
  float* out = (float*)d_out;

  char* p = (char*)d_ws;
  u16* xb     = (u16*)p; p += (size_t)8192 * 2048 * 2;   // x bf16; later reused as att
  u16* wqkvT  = (u16*)p; p += (size_t)6144 * 2048 * 2;
  u16* wprojT = (u16*)p; p += (size_t)2048 * 2048 * 2;
  u16* qb     = (u16*)p; p += (size_t)64 * 2048 * 128 * 2;
  u16* kb     = (u16*)p; p += (size_t)64 * 2048 * 128 * 2;
  u16* vtb    = (u16*)p; p += (size_t)64 * 2048 * 128 * 2;  // total 160 MiB

  k_cvt<<<2048, 256, 0, stream>>>(x, xb, (8192 * 2048) / 4);
  k_tcvt<<<dim3(6144 / 64, 2048 / 64), 256, 0, stream>>>(w_qkv, wqkvT, 2048, 6144);
  k_tcvt<<<dim3(2048 / 64, 2048 / 64), 256, 0, stream>>>(w_proj, wprojT, 2048, 2048);
  k_gemm<0, 24><<<768, 512, 0, stream>>>(xb, wqkvT, b_qkv, qb, kb, vtb, nullptr);
  k_attn<<<dim3(64, 8), 512, 0, stream>>>(qb, kb, vtb, xb);
  k_gemm<1, 8><<<256, 512, 0, stream>>>(xb, wprojT, b_proj, nullptr, nullptr, nullptr, out);
}